// Round 2
// baseline (322.125 us; speedup 1.0000x reference)
//
#include <hip/hip_runtime.h>
#include <math.h>

// Problem: B=16, LQ=1024, LK=1024, DK=256, DV=256, fp32 in/out, mask int32.
// Identity: softmax_k(q_s + k_s with mask) == mask-weighted softmax of k_s alone
// (q_s cancels; masked entries are exactly -1e9 -> weight 0). query never read.
// k_s ~ N(0,256) => softmax mass concentrates in top ~30-60 keys; walk an
// approximately-descending list in 64-wide chunks until provable remaining
// mass <= 1e-5 * Z.
//
// R1: bitonic sort -> counting-sort select_kernel (~20us saved).
// R2: attn_kernel restructured. Old version was LDS-issue-bound (3-4 ds_reads
// per inner iteration for wave-uniform values; 76us, VALUBusy 25%, HBM 9%).
// New version: all wave-uniform values (e, idx, mask[row][k]) come in via
// SCALAR loads (uniform addresses -> s_load, scalar cache, no LDS pipe, no
// VALU); V read directly from global (top-64 rows = 64KB/batch, L2-resident
// across the 64 blocks of a batch -- LDS staging was pure overhead). No LDS,
// no __syncthreads, 1 wave = 1 q-row, 256-thread blocks -> 8 blocks/CU.

#define NB     16
#define NL     1024     // LQ == LK
#define ND     256      // DK == DV
#define NBKT   128      // buckets of width 1.0 in log-space; e-ratio <= e per bucket

// ---------------- Kernel A: ks[b,k] = dot(key[b,k,:], w) -----------------
__global__ __launch_bounds__(256)
void ks_kernel(const float* __restrict__ key, const float* __restrict__ w,
               float* __restrict__ ks) {
    int wid  = threadIdx.x >> 6;
    int lane = threadIdx.x & 63;
    int row  = blockIdx.x * 4 + wid;               // 0 .. NB*NL-1
    const float4* krow = (const float4*)(key + (size_t)row * ND);
    float4 kv = krow[lane];
    float4 wv = ((const float4*)w)[lane];
    float p = kv.x * wv.x + kv.y * wv.y + kv.z * wv.z + kv.w * wv.w;
    #pragma unroll
    for (int off = 32; off > 0; off >>= 1)
        p += __shfl_xor(p, off, 64);
    if (lane == 0) ks[row] = p;
}

// ------- Kernel B: per batch: max, e=exp(ks-m), counting sort by -------
// ------- bucket floor(m-v), exact suffix mass at chunk boundaries -------
// Order within a bucket is arbitrary (weights differ by <= e), which is fine:
// attn processes whole 64-entry chunks and breaks on the EXACT remaining-mass
// bound rem[], computed here from the actual gathered order.
// Output: pk[b*NL+p] = (e, idx-as-float) packed for single s_load_dwordx2.
__global__ __launch_bounds__(1024)
void select_kernel(const float* __restrict__ ks,
                   float2* __restrict__ pk, float* __restrict__ rem) {
    __shared__ float red[NL];      // max-reduce scratch
    __shared__ float se[NL];       // gathered e values (bucket order)
    __shared__ int   cnt[NBKT];    // histogram
    __shared__ int   cur[NBKT];    // scan -> scatter cursors
    __shared__ float csum[16];     // per-chunk sums
    const int b = blockIdx.x;
    const int t = threadIdx.x;
    const int lane = t & 63;
    const int wid  = t >> 6;

    float v = ks[b * NL + t];

    // block max
    red[t] = v;
    __syncthreads();
    for (int off = 512; off > 0; off >>= 1) {
        if (t < off) red[t] = fmaxf(red[t], red[t + off]);
        __syncthreads();
    }
    const float m = red[0];
    __syncthreads();

    const float e = __expf(v - m);          // e in (0,1]

    // histogram of bucket = clamp(floor(m - v), 0, NBKT-1)
    if (t < NBKT) cnt[t] = 0;
    __syncthreads();
    int bkt = (int)fminf(m - v, (float)(NBKT - 1));   // m - v >= 0
    atomicAdd(&cnt[bkt], 1);
    __syncthreads();

    // inclusive scan of cnt (Hillis-Steele over 128 entries)
    if (t < NBKT) cur[t] = cnt[t];
    __syncthreads();
    for (int off = 1; off < NBKT; off <<= 1) {
        int add = 0;
        if (t < NBKT && t >= off) add = cur[t - off];
        __syncthreads();
        if (t < NBKT) cur[t] += add;
        __syncthreads();
    }
    // exclusive prefix -> scatter cursor base
    if (t < NBKT) cur[t] -= cnt[t];
    __syncthreads();

    // scatter (bijective: every t gets a unique p in [0, NL))
    int p = atomicAdd(&cur[bkt], 1);
    se[p] = e;
    pk[b * NL + p] = make_float2(e, __int_as_float(t));
    __syncthreads();

    // per-chunk sums: wave w reduces chunk w (64 entries)
    float s = se[wid * 64 + lane];
    #pragma unroll
    for (int off = 32; off > 0; off >>= 1)
        s += __shfl_xor(s, off, 64);
    if (lane == 0) csum[wid] = s;
    __syncthreads();

    // suffix masses at the 16 boundary slots attn actually reads:
    // rem[b*NL + c*64 + 63] = sum of chunk sums for chunks > c
    if (t == 0) {
        float run = 0.0f;
        for (int c = 15; c >= 0; --c) {
            rem[b * NL + c * 64 + 63] = run;
            run += csum[c];
        }
    }
}

// ---------------- Kernel C: out[b,q,:] = sum_k p * value[b,k,:] ----------
// 256 threads = 4 waves = 4 q-rows. One wave owns one row; lane owns float4
// of the 256-wide output. Per entry (wave-uniform): s_load (e,idx) pair,
// s_load mask[row][k]; only if unmasked, vector-load V row (L2-hot) and FMA.
// No LDS, no barriers. Chunked walk with exact remaining-mass break.
__global__ __launch_bounds__(256)
void attn_kernel(const float* __restrict__ value, const int* __restrict__ mask,
                 const float2* __restrict__ pk, const float* __restrict__ rem,
                 float* __restrict__ out) {
    const int wid  = threadIdx.x >> 6;
    const int lane = threadIdx.x & 63;
    const int row  = blockIdx.x * 4 + wid;    // 0 .. NB*NL-1
    const int b    = row >> 10;
    const int base = b << 10;

    const float4*  vbase = (const float4*)(value + ((size_t)b << 10) * ND);
    const int*     mrow  = mask + (size_t)row * NL;
    const float2*  pk_g  = pk + base;

    float4 acc = make_float4(0.f, 0.f, 0.f, 0.f);
    float Z = 0.0f;
    bool done = false;

    for (int c = 0; c < 16 && !done; ++c) {
        const int o = c * 64;
        #pragma unroll 8
        for (int i = 0; i < 64; ++i) {
            float2 p = pk_g[o + i];              // uniform addr -> s_load_dwordx2
            int   k  = __float_as_int(p.y);
            if (mrow[k] != 0) {                  // uniform -> s_load, wave-uniform branch
                float ei = p.x;
                Z += ei;
                float4 v = vbase[(size_t)k * 64 + lane];
                acc.x += ei * v.x; acc.y += ei * v.y;
                acc.z += ei * v.z; acc.w += ei * v.w;
            }
        }
        done = (rem[base + o + 63] <= 1e-5f * Z);   // Z==0 -> rem>0 -> continue
    }

    float4* orow = (float4*)(out + (size_t)row * ND);
    if (Z > 0.0f) {
        float inv = 1.0f / Z;
        orow[lane] = make_float4(acc.x * inv, acc.y * inv, acc.z * inv, acc.w * inv);
    } else {
        // all-masked row: reference softmax over constant -1e9 -> uniform avg
        float4 s = make_float4(0.f, 0.f, 0.f, 0.f);
        for (int k = 0; k < NL; ++k) {
            float4 v = vbase[(size_t)k * 64 + lane];
            s.x += v.x; s.y += v.y; s.z += v.z; s.w += v.w;
        }
        const float inv = 1.0f / (float)NL;
        orow[lane] = make_float4(s.x * inv, s.y * inv, s.z * inv, s.w * inv);
    }
}

extern "C" void kernel_launch(void* const* d_in, const int* in_sizes, int n_in,
                              void* d_out, int out_size, void* d_ws, size_t ws_size,
                              hipStream_t stream) {
    // setup_inputs order: query, key, value, w, mask   (query unused!)
    const float* key   = (const float*)d_in[1];
    const float* value = (const float*)d_in[2];
    const float* w     = (const float*)d_in[3];
    const int*   mask  = (const int*)d_in[4];
    float*       outp  = (float*)d_out;

    float*  ks  = (float*)d_ws;                  // 16*1024 f32
    float2* pkb = (float2*)(ks + NB * NL);       // 16*1024 f32x2 (e, idx) bucket-desc
    float*  rem = (float*)(pkb + NB * NL);       // 16*1024 f32 suffix masses

    ks_kernel    <<<NB * NL / 4, 256, 0, stream>>>(key, w, ks);
    select_kernel<<<NB, 1024, 0, stream>>>(ks, pkb, rem);
    attn_kernel  <<<NB * NL / 4, 256, 0, stream>>>(value, mask, pkb, rem, outp);
}

// Round 3
// 175.823 us; speedup vs baseline: 1.8321x; 1.8321x over previous
//
#include <hip/hip_runtime.h>
#include <math.h>

// Problem: B=16, LQ=1024, LK=1024, DK=256, DV=256, fp32 in/out, mask int32.
// Identity: softmax_k(q_s + k_s with mask) == mask-weighted softmax of k_s alone
// (q_s cancels; masked entries are exactly -1e9 -> weight 0). query never read.
// k_s ~ N(0,256) => softmax mass concentrates in top ~30-60 keys; walk an
// approximately-descending list in 64-wide chunks until provable remaining
// mass <= 1e-5 * Z.
//
// R1: bitonic sort -> counting-sort select_kernel.
// R2 (FAILED, 218us): per-iteration dependent scalar loads serialized on L2
// latency. Lesson: addresses must be available lane-parallel upfront.
// R3: metadata gathered lane-parallel (1 float2 + 1 int4x4 load), mask bit via
// one ds_bpermute, actives compacted to low lanes via bijective ds_permute,
// then a branch-free readlane walk with independent global V loads (L2-hot,
// top-64 rows = 64KB/batch). No LDS arrays, no barriers.

#define NB     16
#define NL     1024     // LQ == LK
#define ND     256      // DK == DV
#define NBKT   128      // buckets of width 1.0 in log-space; e-ratio <= e per bucket

// ---------------- Kernel A: ks[b,k] = dot(key[b,k,:], w) -----------------
__global__ __launch_bounds__(256)
void ks_kernel(const float* __restrict__ key, const float* __restrict__ w,
               float* __restrict__ ks) {
    int wid  = threadIdx.x >> 6;
    int lane = threadIdx.x & 63;
    int row  = blockIdx.x * 4 + wid;               // 0 .. NB*NL-1
    const float4* krow = (const float4*)(key + (size_t)row * ND);
    float4 kv = krow[lane];
    float4 wv = ((const float4*)w)[lane];
    float p = kv.x * wv.x + kv.y * wv.y + kv.z * wv.z + kv.w * wv.w;
    #pragma unroll
    for (int off = 32; off > 0; off >>= 1)
        p += __shfl_xor(p, off, 64);
    if (lane == 0) ks[row] = p;
}

// ------- Kernel B: per batch: max, e=exp(ks-m), counting sort by -------
// ------- bucket floor(m-v), exact suffix mass at chunk boundaries -------
// Order within a bucket is arbitrary (weights differ by <= e); attn processes
// whole 64-entry chunks and breaks on the EXACT remaining-mass bound rem[],
// computed here from the actual gathered order.
// Output: pk[b*NL+p] = (e, idx-as-float) packed pairs.
__global__ __launch_bounds__(1024)
void select_kernel(const float* __restrict__ ks,
                   float2* __restrict__ pk, float* __restrict__ rem) {
    __shared__ float red[NL];      // max-reduce scratch
    __shared__ float se[NL];       // gathered e values (bucket order)
    __shared__ int   cnt[NBKT];    // histogram
    __shared__ int   cur[NBKT];    // scan -> scatter cursors
    __shared__ float csum[16];     // per-chunk sums
    const int b = blockIdx.x;
    const int t = threadIdx.x;
    const int lane = t & 63;
    const int wid  = t >> 6;

    float v = ks[b * NL + t];

    // block max
    red[t] = v;
    __syncthreads();
    for (int off = 512; off > 0; off >>= 1) {
        if (t < off) red[t] = fmaxf(red[t], red[t + off]);
        __syncthreads();
    }
    const float m = red[0];
    __syncthreads();

    const float e = __expf(v - m);          // e in (0,1]

    // histogram of bucket = clamp(floor(m - v), 0, NBKT-1)
    if (t < NBKT) cnt[t] = 0;
    __syncthreads();
    int bkt = (int)fminf(m - v, (float)(NBKT - 1));   // m - v >= 0
    atomicAdd(&cnt[bkt], 1);
    __syncthreads();

    // inclusive scan of cnt (Hillis-Steele over 128 entries)
    if (t < NBKT) cur[t] = cnt[t];
    __syncthreads();
    for (int off = 1; off < NBKT; off <<= 1) {
        int add = 0;
        if (t < NBKT && t >= off) add = cur[t - off];
        __syncthreads();
        if (t < NBKT) cur[t] += add;
        __syncthreads();
    }
    // exclusive prefix -> scatter cursor base
    if (t < NBKT) cur[t] -= cnt[t];
    __syncthreads();

    // scatter (bijective: every t gets a unique p in [0, NL))
    int p = atomicAdd(&cur[bkt], 1);
    se[p] = e;
    pk[b * NL + p] = make_float2(e, __int_as_float(t));
    __syncthreads();

    // per-chunk sums: wave w reduces chunk w (64 entries)
    float s = se[wid * 64 + lane];
    #pragma unroll
    for (int off = 32; off > 0; off >>= 1)
        s += __shfl_xor(s, off, 64);
    if (lane == 0) csum[wid] = s;
    __syncthreads();

    // suffix masses at the 16 boundary slots attn actually reads:
    // rem[b*NL + c*64 + 63] = sum of chunk sums for chunks > c
    if (t == 0) {
        float run = 0.0f;
        for (int c = 15; c >= 0; --c) {
            rem[b * NL + c * 64 + 63] = run;
            run += csum[c];
        }
    }
}

// ---------------- Kernel C: out[b,q,:] = sum_k p * value[b,k,:] ----------
// 256 threads = 4 waves = 4 q-rows. One wave owns one row; lane owns float4
// of the 256-wide output. Per chunk: lane i holds entry i's (e,k); mask bit
// resolved via one ds_bpermute from the 16-bits-per-lane mask registers;
// actives compacted to low lanes (bijective ds_permute, all lanes write a
// unique dest -> no exec hazards); branch-free walk over i<NA with readlane
// broadcast and independent global V loads (L2-hot).
__global__ __launch_bounds__(256)
void attn_kernel(const float* __restrict__ value, const int* __restrict__ mask,
                 const float2* __restrict__ pk, const float* __restrict__ rem,
                 float* __restrict__ out) {
    const int wid  = threadIdx.x >> 6;
    const int lane = threadIdx.x & 63;
    const int row  = blockIdx.x * 4 + wid;    // 0 .. NB*NL-1
    const int b    = row >> 10;
    const int base = b << 10;

    const float4*  vbase = (const float4*)(value + ((size_t)b << 10) * ND);
    const float2*  pk_g  = pk + base;

    // mask row -> 16 bits per lane: lane owns columns [lane*16, lane*16+16)
    const int4* mrow4 = (const int4*)(mask + (size_t)row * NL);
    unsigned int bits = 0;
    #pragma unroll
    for (int j = 0; j < 4; ++j) {
        int4 m = mrow4[lane * 4 + j];
        bits |= (m.x != 0 ? 1u : 0u) << (j * 4 + 0);
        bits |= (m.y != 0 ? 1u : 0u) << (j * 4 + 1);
        bits |= (m.z != 0 ? 1u : 0u) << (j * 4 + 2);
        bits |= (m.w != 0 ? 1u : 0u) << (j * 4 + 3);
    }

    float4 acc = make_float4(0.f, 0.f, 0.f, 0.f);
    float Z = 0.0f;
    bool done = false;

    for (int c = 0; c < 16 && !done; ++c) {
        // lane i holds entry (c*64 + i)
        float2 p = pk_g[c * 64 + lane];          // coalesced 512B
        float e  = p.x;
        int   k  = __float_as_int(p.y);

        // mask bit for column k lives in lane (k>>4), bit (k&15)
        unsigned int bk = (unsigned int)
            __builtin_amdgcn_ds_bpermute((k >> 4) << 2, (int)bits);
        bool mb = (bk >> (k & 15)) & 1u;

        unsigned long long bm = __ballot(mb);
        int NA = __popcll(bm);

        // Z += sum of masked e (butterfly; result uniform)
        float em = mb ? e : 0.0f;
        #pragma unroll
        for (int off = 32; off > 0; off >>= 1)
            em += __shfl_xor(em, off, 64);
        Z += em;

        if (NA > 0) {
            // bijective compaction: actives -> [0,NA), inactives -> [NA,64)
            unsigned int lo = (unsigned int)bm, hi = (unsigned int)(bm >> 32);
            int cntA = __builtin_amdgcn_mbcnt_hi(hi,
                       __builtin_amdgcn_mbcnt_lo(lo, 0));   // set bits below lane
            int dest = mb ? cntA : (NA + (lane - cntA));
            int ec = __builtin_amdgcn_ds_permute(dest << 2, __float_as_int(e));
            int kc = __builtin_amdgcn_ds_permute(dest << 2, k);

            // branch-free walk over active entries
            #pragma unroll 4
            for (int i = 0; i < NA; ++i) {
                float es  = __int_as_float(__builtin_amdgcn_readlane(ec, i));
                int   ksv = __builtin_amdgcn_readlane(kc, i);
                float4 v  = vbase[(size_t)ksv * 64 + lane];
                acc.x += es * v.x; acc.y += es * v.y;
                acc.z += es * v.z; acc.w += es * v.w;
            }
        }
        done = (rem[base + c * 64 + 63] <= 1e-5f * Z);   // Z==0 -> rem>0 -> continue
    }

    float4* orow = (float4*)(out + (size_t)row * ND);
    if (Z > 0.0f) {
        float inv = 1.0f / Z;
        orow[lane] = make_float4(acc.x * inv, acc.y * inv, acc.z * inv, acc.w * inv);
    } else {
        // all-masked row: reference softmax over constant -1e9 -> uniform avg
        float4 s = make_float4(0.f, 0.f, 0.f, 0.f);
        for (int k = 0; k < NL; ++k) {
            float4 v = vbase[(size_t)k * 64 + lane];
            s.x += v.x; s.y += v.y; s.z += v.z; s.w += v.w;
        }
        const float inv = 1.0f / (float)NL;
        orow[lane] = make_float4(s.x * inv, s.y * inv, s.z * inv, s.w * inv);
    }
}

extern "C" void kernel_launch(void* const* d_in, const int* in_sizes, int n_in,
                              void* d_out, int out_size, void* d_ws, size_t ws_size,
                              hipStream_t stream) {
    // setup_inputs order: query, key, value, w, mask   (query unused!)
    const float* key   = (const float*)d_in[1];
    const float* value = (const float*)d_in[2];
    const float* w     = (const float*)d_in[3];
    const int*   mask  = (const int*)d_in[4];
    float*       outp  = (float*)d_out;

    float*  ks  = (float*)d_ws;                  // 16*1024 f32
    float2* pkb = (float2*)(ks + NB * NL);       // 16*1024 f32x2 (e, idx) bucket-desc
    float*  rem = (float*)(pkb + NB * NL);       // 16*1024 f32 suffix masses

    ks_kernel    <<<NB * NL / 4, 256, 0, stream>>>(key, w, ks);
    select_kernel<<<NB, 1024, 0, stream>>>(ks, pkb, rem);
    attn_kernel  <<<NB * NL / 4, 256, 0, stream>>>(value, mask, pkb, rem, outp);
}

// Round 4
// 166.501 us; speedup vs baseline: 1.9347x; 1.0560x over previous
//
#include <hip/hip_runtime.h>
#include <math.h>

// Problem: B=16, LQ=1024, LK=1024, DK=256, DV=256, fp32 in/out, mask int32.
// Identity: softmax_k(q_s + k_s with mask) == mask-weighted softmax of k_s alone
// (q_s cancels; masked entries are exactly -1e9 -> weight 0). query never read.
// k_s ~ N(0,256) => softmax mass concentrates in top ~30-60 keys; chunk-0
// (top-64) provably terminates ~all rows (e_64 ~ e^-26 * Z << 1e-5 * Z).
//
// R1: bitonic sort -> counting-sort select_kernel.
// R2 (FAILED, 218us): serial dependent scalar loads -> L2 latency chain.
// R3 (62us): lane-parallel metadata + register compaction, but the walk's
// global V gather stayed latency-bound (rolled loop, 1 load in flight).
// R4: chunk-0 V rows (shared by all rows of a batch) staged once per block in
// LDS (64KB, 2 blocks/CU); walk = ds_read_b128 (12cy tput) unrolled x4 with 4
// independent accumulators; Z accumulated from readlane'd weights (no
// butterfly). Metadata stays in registers as in R3. Chunks >=1 keep the
// (almost never taken) R3 global path.

#define NB     16
#define NL     1024     // LQ == LK
#define ND     256      // DK == DV
#define NBKT   128      // buckets of width 1.0 in log-space

// ---------------- Kernel A: ks[b,k] = dot(key[b,k,:], w) -----------------
__global__ __launch_bounds__(256)
void ks_kernel(const float* __restrict__ key, const float* __restrict__ w,
               float* __restrict__ ks) {
    int wid  = threadIdx.x >> 6;
    int lane = threadIdx.x & 63;
    int row  = blockIdx.x * 4 + wid;               // 0 .. NB*NL-1
    const float4* krow = (const float4*)(key + (size_t)row * ND);
    float4 kv = krow[lane];
    float4 wv = ((const float4*)w)[lane];
    float p = kv.x * wv.x + kv.y * wv.y + kv.z * wv.z + kv.w * wv.w;
    #pragma unroll
    for (int off = 32; off > 0; off >>= 1)
        p += __shfl_xor(p, off, 64);
    if (lane == 0) ks[row] = p;
}

// ------- Kernel B: per batch: max, e=exp(ks-m), counting sort by -------
// ------- bucket floor(m-v), exact suffix mass at chunk boundaries -------
__global__ __launch_bounds__(1024)
void select_kernel(const float* __restrict__ ks,
                   float2* __restrict__ pk, float* __restrict__ rem) {
    __shared__ float red[NL];      // max-reduce scratch
    __shared__ float se[NL];       // gathered e values (bucket order)
    __shared__ int   cnt[NBKT];    // histogram
    __shared__ int   cur[NBKT];    // scan -> scatter cursors
    __shared__ float csum[16];     // per-chunk sums
    const int b = blockIdx.x;
    const int t = threadIdx.x;
    const int lane = t & 63;
    const int wid  = t >> 6;

    float v = ks[b * NL + t];

    // block max
    red[t] = v;
    __syncthreads();
    for (int off = 512; off > 0; off >>= 1) {
        if (t < off) red[t] = fmaxf(red[t], red[t + off]);
        __syncthreads();
    }
    const float m = red[0];
    __syncthreads();

    const float e = __expf(v - m);          // e in (0,1]

    // histogram of bucket = clamp(floor(m - v), 0, NBKT-1)
    if (t < NBKT) cnt[t] = 0;
    __syncthreads();
    int bkt = (int)fminf(m - v, (float)(NBKT - 1));   // m - v >= 0
    atomicAdd(&cnt[bkt], 1);
    __syncthreads();

    // inclusive scan of cnt (Hillis-Steele over 128 entries)
    if (t < NBKT) cur[t] = cnt[t];
    __syncthreads();
    for (int off = 1; off < NBKT; off <<= 1) {
        int add = 0;
        if (t < NBKT && t >= off) add = cur[t - off];
        __syncthreads();
        if (t < NBKT) cur[t] += add;
        __syncthreads();
    }
    // exclusive prefix -> scatter cursor base
    if (t < NBKT) cur[t] -= cnt[t];
    __syncthreads();

    // scatter (bijective: every t gets a unique p in [0, NL))
    int p = atomicAdd(&cur[bkt], 1);
    se[p] = e;
    pk[b * NL + p] = make_float2(e, __int_as_float(t));
    __syncthreads();

    // per-chunk sums: wave w reduces chunk w (64 entries)
    float s = se[wid * 64 + lane];
    #pragma unroll
    for (int off = 32; off > 0; off >>= 1)
        s += __shfl_xor(s, off, 64);
    if (lane == 0) csum[wid] = s;
    __syncthreads();

    // suffix masses at the 16 boundary slots attn actually reads
    if (t == 0) {
        float run = 0.0f;
        for (int c = 15; c >= 0; --c) {
            rem[b * NL + c * 64 + 63] = run;
            run += csum[c];
        }
    }
}

// ---------------- Kernel C: out[b,q,:] = sum_k p * value[b,k,:] ----------
// 1024 threads = 16 waves = 16 q-rows (same batch). Chunk-0 V rows staged in
// LDS once per block; per-row metadata in registers (R3 path); walk reads
// ds_read_b128 with 4 independent accumulators.
__global__ __launch_bounds__(1024)
void attn_kernel(const float* __restrict__ value, const int* __restrict__ mask,
                 const float2* __restrict__ pk, const float* __restrict__ rem,
                 float* __restrict__ out) {
    __shared__ float lds_V[64 * ND];          // 64 KB: chunk-0 value rows

    const int wid  = threadIdx.x >> 6;
    const int lane = threadIdx.x & 63;
    const int row  = blockIdx.x * 16 + wid;   // 0 .. NB*NL-1 (16 rows, same b)
    const int b    = row >> 10;
    const int base = b << 10;

    const float4* vbase = (const float4*)(value + ((size_t)b << 10) * ND);
    const float2* pk_g  = pk + base;

    // chunk-0 metadata, lane-parallel: lane i holds entry i's (e, k)
    float2 p0 = pk_g[lane];
    float e0 = p0.x;
    int   k0 = __float_as_int(p0.y);

    // stage chunk-0 V rows: wave w stages slots 4w..4w+3 (coalesced 1KB each)
    #pragma unroll
    for (int j = 0; j < 4; ++j) {
        int s  = wid * 4 + j;
        int ks = __builtin_amdgcn_readlane(k0, s);
        ((float4*)lds_V)[s * 64 + lane] = vbase[(size_t)ks * 64 + lane];
    }

    // mask row -> 16 bits per lane: lane owns columns [lane*16, lane*16+16)
    const int4* mrow4 = (const int4*)(mask + (size_t)row * NL);
    unsigned int bits = 0;
    #pragma unroll
    for (int j = 0; j < 4; ++j) {
        int4 m = mrow4[lane * 4 + j];
        bits |= (m.x != 0 ? 1u : 0u) << (j * 4 + 0);
        bits |= (m.y != 0 ? 1u : 0u) << (j * 4 + 1);
        bits |= (m.z != 0 ? 1u : 0u) << (j * 4 + 2);
        bits |= (m.w != 0 ? 1u : 0u) << (j * 4 + 3);
    }

    __syncthreads();   // lds_V ready

    // ---- chunk 0: mask bit via bpermute, compact (e, slot) to low lanes ----
    unsigned int bk = (unsigned int)
        __builtin_amdgcn_ds_bpermute((k0 >> 4) << 2, (int)bits);
    bool mb = (bk >> (k0 & 15)) & 1u;
    unsigned long long bm = __ballot(mb);
    int NA = __popcll(bm);
    unsigned int blo = (unsigned int)bm, bhi = (unsigned int)(bm >> 32);
    int cntA = __builtin_amdgcn_mbcnt_hi(bhi,
               __builtin_amdgcn_mbcnt_lo(blo, 0));
    int dest = mb ? cntA : (NA + (lane - cntA));
    int ec = __builtin_amdgcn_ds_permute(dest << 2, __float_as_int(e0));
    int sc = __builtin_amdgcn_ds_permute(dest << 2, lane);

    float4 a0 = make_float4(0.f, 0.f, 0.f, 0.f);
    float4 a1 = make_float4(0.f, 0.f, 0.f, 0.f);
    float4 a2 = make_float4(0.f, 0.f, 0.f, 0.f);
    float4 a3 = make_float4(0.f, 0.f, 0.f, 0.f);
    float Z = 0.0f;

    int i = 0;
    for (; i + 4 <= NA; i += 4) {
        int   s0 = __builtin_amdgcn_readlane(sc, i);
        int   s1 = __builtin_amdgcn_readlane(sc, i + 1);
        int   s2 = __builtin_amdgcn_readlane(sc, i + 2);
        int   s3 = __builtin_amdgcn_readlane(sc, i + 3);
        float w0 = __int_as_float(__builtin_amdgcn_readlane(ec, i));
        float w1 = __int_as_float(__builtin_amdgcn_readlane(ec, i + 1));
        float w2 = __int_as_float(__builtin_amdgcn_readlane(ec, i + 2));
        float w3 = __int_as_float(__builtin_amdgcn_readlane(ec, i + 3));
        float4 v0 = ((const float4*)lds_V)[s0 * 64 + lane];
        float4 v1 = ((const float4*)lds_V)[s1 * 64 + lane];
        float4 v2 = ((const float4*)lds_V)[s2 * 64 + lane];
        float4 v3 = ((const float4*)lds_V)[s3 * 64 + lane];
        Z += w0 + w1 + w2 + w3;
        a0.x += w0 * v0.x; a0.y += w0 * v0.y; a0.z += w0 * v0.z; a0.w += w0 * v0.w;
        a1.x += w1 * v1.x; a1.y += w1 * v1.y; a1.z += w1 * v1.z; a1.w += w1 * v1.w;
        a2.x += w2 * v2.x; a2.y += w2 * v2.y; a2.z += w2 * v2.z; a2.w += w2 * v2.w;
        a3.x += w3 * v3.x; a3.y += w3 * v3.y; a3.z += w3 * v3.z; a3.w += w3 * v3.w;
    }
    for (; i < NA; ++i) {
        int   s0 = __builtin_amdgcn_readlane(sc, i);
        float w0 = __int_as_float(__builtin_amdgcn_readlane(ec, i));
        float4 v0 = ((const float4*)lds_V)[s0 * 64 + lane];
        Z += w0;
        a0.x += w0 * v0.x; a0.y += w0 * v0.y; a0.z += w0 * v0.z; a0.w += w0 * v0.w;
    }

    float4 acc = make_float4(a0.x + a1.x + a2.x + a3.x,
                             a0.y + a1.y + a2.y + a3.y,
                             a0.z + a1.z + a2.z + a3.z,
                             a0.w + a1.w + a2.w + a3.w);
    bool done = (rem[base + 63] <= 1e-5f * Z);   // Z==0 -> rem>0 -> continue

    // ---- chunks 1..15 (provably almost never taken): R3 global path ----
    for (int c = 1; c < 16 && !done; ++c) {
        float2 p = pk_g[c * 64 + lane];
        float e  = p.x;
        int   k  = __float_as_int(p.y);
        unsigned int bk2 = (unsigned int)
            __builtin_amdgcn_ds_bpermute((k >> 4) << 2, (int)bits);
        bool mb2 = (bk2 >> (k & 15)) & 1u;
        unsigned long long bm2 = __ballot(mb2);
        int NA2 = __popcll(bm2);
        if (NA2 > 0) {
            unsigned int lo2 = (unsigned int)bm2, hi2 = (unsigned int)(bm2 >> 32);
            int cnt2 = __builtin_amdgcn_mbcnt_hi(hi2,
                       __builtin_amdgcn_mbcnt_lo(lo2, 0));
            int d2 = mb2 ? cnt2 : (NA2 + (lane - cnt2));
            int ec2 = __builtin_amdgcn_ds_permute(d2 << 2, __float_as_int(e));
            int kc2 = __builtin_amdgcn_ds_permute(d2 << 2, k);
            #pragma unroll 4
            for (int t = 0; t < NA2; ++t) {
                float es  = __int_as_float(__builtin_amdgcn_readlane(ec2, t));
                int   ksv = __builtin_amdgcn_readlane(kc2, t);
                float4 v  = vbase[(size_t)ksv * 64 + lane];
                Z += es;
                acc.x += es * v.x; acc.y += es * v.y;
                acc.z += es * v.z; acc.w += es * v.w;
            }
        }
        done = (rem[base + c * 64 + 63] <= 1e-5f * Z);
    }

    float4* orow = (float4*)(out + (size_t)row * ND);
    if (Z > 0.0f) {
        float inv = 1.0f / Z;
        orow[lane] = make_float4(acc.x * inv, acc.y * inv, acc.z * inv, acc.w * inv);
    } else {
        // all-masked row: reference softmax over constant -1e9 -> uniform avg
        float4 s = make_float4(0.f, 0.f, 0.f, 0.f);
        for (int k = 0; k < NL; ++k) {
            float4 v = vbase[(size_t)k * 64 + lane];
            s.x += v.x; s.y += v.y; s.z += v.z; s.w += v.w;
        }
        const float inv = 1.0f / (float)NL;
        orow[lane] = make_float4(s.x * inv, s.y * inv, s.z * inv, s.w * inv);
    }
}

extern "C" void kernel_launch(void* const* d_in, const int* in_sizes, int n_in,
                              void* d_out, int out_size, void* d_ws, size_t ws_size,
                              hipStream_t stream) {
    // setup_inputs order: query, key, value, w, mask   (query unused!)
    const float* key   = (const float*)d_in[1];
    const float* value = (const float*)d_in[2];
    const float* w     = (const float*)d_in[3];
    const int*   mask  = (const int*)d_in[4];
    float*       outp  = (float*)d_out;

    float*  ks  = (float*)d_ws;                  // 16*1024 f32
    float2* pkb = (float2*)(ks + NB * NL);       // 16*1024 f32x2 (e, idx) bucket-desc
    float*  rem = (float*)(pkb + NB * NL);       // 16*1024 f32 suffix masses

    ks_kernel    <<<NB * NL / 4, 256, 0, stream>>>(key, w, ks);
    select_kernel<<<NB, 1024, 0, stream>>>(ks, pkb, rem);
    attn_kernel  <<<NB * NL / 16, 1024, 0, stream>>>(value, mask, pkb, rem, outp);
}